// Round 3
// baseline (26.268 us; speedup 1.0000x reference)
//
#include <hip/hip_runtime.h>

#define DEV __device__ __forceinline__

typedef _Float16 h2 __attribute__((ext_vector_type(2)));

DEV float fast_rcp(float x) { return __builtin_amdgcn_rcpf(x); }

DEV float fexp2(float x) {
#if __has_builtin(__builtin_amdgcn_exp2f)
    return __builtin_amdgcn_exp2f(x);
#else
    float r; asm("v_exp_f32 %0, %1" : "=v"(r) : "v"(x)); return r;
#endif
}

DEV float dot2acc(h2 a, h2 b, float c) {
#if __has_builtin(__builtin_amdgcn_fdot2)
    return __builtin_amdgcn_fdot2(a, b, c, false);
#else
    return c + (float)a.x * (float)b.x + (float)a.y * (float)b.y;
#endif
}

// f32 += f16(lo/hi half of packed pair) * f32  -- single v_fma_mix_f32
DEV float fma_mix_lo(unsigned p, float b, float c) {
    float d;
    asm("v_fma_mix_f32 %0, %1, %2, %3 op_sel_hi:[1,0,0]"
        : "=v"(d) : "v"(p), "v"(b), "v"(c));
    return d;
}
DEV float fma_mix_hi(unsigned p, float b, float c) {
    float d;
    asm("v_fma_mix_f32 %0, %1, %2, %3 op_sel:[1,0,0] op_sel_hi:[1,0,0]"
        : "=v"(d) : "v"(p), "v"(b), "v"(c));
    return d;
}

// tanh(x) = 1 - 2/(exp2(2*log2e*x)+1); saturates correctly at +/-inf.
DEV float fast_tanh(float x) {
    float e = fexp2(x * 2.885390082f);
    return 1.0f - 2.0f * fast_rcp(e + 1.0f);
}
DEV float fast_sigmoid(float x) {
    return fast_rcp(1.0f + fexp2(x * -1.442695041f));
}

template <int IN, int OUT, bool HAS_BIAS, bool TANH>
DEV void layer(const float* __restrict__ w, const float* __restrict__ b,
               const float (&in)[IN], float (&out)[OUT]) {
    #pragma unroll
    for (int o = 0; o < OUT; ++o) {
        float acc = HAS_BIAS ? b[o] : 0.0f;
        #pragma unroll
        for (int i = 0; i < IN; ++i) acc = fmaf(in[i], w[o * IN + i], acc);
        out[o] = TANH ? fast_tanh(acc) : acc;
    }
}

// Compute outputs [obase, obase+HALF) of a layer. obase is wave-uniform (SGPR)
// so weight reads stay scalar s_loads.
template <int IN, int HALF>
DEV void half_layer(const float* __restrict__ w, const float* __restrict__ b,
                    int obase, const float (&in)[IN], float (&out)[HALF]) {
    #pragma unroll
    for (int o = 0; o < HALF; ++o) {
        float acc = b[obase + o];
        #pragma unroll
        for (int i = 0; i < IN; ++i) acc = fmaf(in[i], w[(obase + o) * IN + i], acc);
        out[o] = fast_tanh(acc);
    }
}

// Exchange halves with the partner thread (same token, other wave) via LDS.
// Row stride 17 floats -> 2 lanes/bank (free). lou is wave-uniform, so the
// assembly of `full` uses only compile-time indices in each branch (no scratch).
template <int HALF>
DEV void exchange(float* __restrict__ buf, int s, int lou,
                  const float (&mine)[HALF], float (&full)[2 * HALF]) {
    float* row = buf + s * 17;
    #pragma unroll
    for (int o = 0; o < HALF; ++o) row[lou * HALF + o] = mine[o];
    __syncthreads();
    if (lou == 0) {
        #pragma unroll
        for (int o = 0; o < HALF; ++o) { full[o] = mine[o]; full[HALF + o] = row[HALF + o]; }
    } else {
        #pragma unroll
        for (int o = 0; o < HALF; ++o) { full[o] = row[o]; full[HALF + o] = mine[o]; }
    }
}

__global__ __launch_bounds__(256, 8)
void qcnn_fused_kernel(const float* __restrict__ x,
                       const float* __restrict__ w_fm, const float* __restrict__ b_fm,
                       const float* __restrict__ w_c1, const float* __restrict__ b_c1,
                       const float* __restrict__ w_p1, const float* __restrict__ b_p1,
                       const float* __restrict__ w_c2, const float* __restrict__ b_c2,
                       const float* __restrict__ w_p2, const float* __restrict__ b_p2,
                       const float* __restrict__ w_c3, const float* __restrict__ b_c3,
                       const float* __restrict__ w_q,  const float* __restrict__ w_k,
                       const float* __restrict__ w_v,
                       const float* __restrict__ w_fc, const float* __restrict__ b_fc,
                       float* __restrict__ out) {
    const int b    = blockIdx.x;
    const int t    = threadIdx.x;        // 0..255
    const int lane = t & 63;
    const int wave = t >> 6;             // 0..3
    const int lo   = wave & 1;           // half index, uniform within wave
    const int lou  = __builtin_amdgcn_readfirstlane(lo);
    const int s    = (wave >> 1) * 64 + lane;   // token 0..127

    __shared__ __align__(16) float bufA[128 * 17];   // 8704 B
    __shared__ float bufB[128 * 17];                 // 8704 B
    // kv/q buffers alias bufA: all bufA traffic is finished before barrier 4,
    // kv/q writes happen after it.
    uint4* kvbuf = (uint4*)bufA;            // 128 * 16 B = 2048 B
    uint2* qbuf  = (uint2*)(bufA + 512);    // 128 * 8  B = 1024 B

    // ---- full x row per thread (partner loads it too; L2 absorbs the 2x) ----
    const float* xp = x + ((size_t)b * 128 + (size_t)s) * 8;
    float4 x0 = *reinterpret_cast<const float4*>(xp);
    float4 x1 = *reinterpret_cast<const float4*>(xp + 4);
    float xin[8] = {x0.x, x0.y, x0.z, x0.w, x1.x, x1.y, x1.z, x1.w};

    // ---- split MLP: this thread computes output half [lou*H, lou*H+H) ----
    float h1h[8], h1[16];
    half_layer<8, 8>(w_fm, b_fm, lou * 8, xin, h1h);
    exchange<8>(bufA, s, lou, h1h, h1);               // barrier 1

    float h2h[8], h2f[16];
    half_layer<16, 8>(w_c1, b_c1, lou * 8, h1, h2h);
    exchange<8>(bufB, s, lou, h2h, h2f);              // barrier 2

    float h3h[6], h3[12];
    half_layer<16, 6>(w_p1, b_p1, lou * 6, h2f, h3h);
    exchange<6>(bufA, s, lou, h3h, h3);               // barrier 3

    float h4h[4], h4[8];
    half_layer<12, 4>(w_c2, b_c2, lou * 4, h3, h4h);
    exchange<4>(bufB, s, lou, h4h, h4);               // barrier 4

    // ---- small tail computed redundantly (cheaper than 2 more exchanges) ----
    float h5[4], h6[4];
    layer<8, 4, true, true>(w_p2, b_p2, h4, h5);
    layer<4, 4, true, true>(w_c3, b_c3, h5, h6);

    const float QS = 0.7213475204f;   // log2(e)/sqrt(4): folds softmax scale + exp->exp2
    if (lou == 0) {
        float kk[4], vv[4];
        layer<4, 4, false, false>(w_k, nullptr, h6, kk);
        layer<4, 4, false, false>(w_v, nullptr, h6, vv);
        h2 pk01 = {(_Float16)kk[0], (_Float16)kk[1]};
        h2 pk23 = {(_Float16)kk[2], (_Float16)kk[3]};
        h2 pv01 = {(_Float16)vv[0], (_Float16)vv[1]};
        h2 pv23 = {(_Float16)vv[2], (_Float16)vv[3]};
        uint4 pk;
        pk.x = __builtin_bit_cast(unsigned, pk01);
        pk.y = __builtin_bit_cast(unsigned, pk23);
        pk.z = __builtin_bit_cast(unsigned, pv01);
        pk.w = __builtin_bit_cast(unsigned, pv23);
        kvbuf[s] = pk;
    } else {
        float qv[4];
        layer<4, 4, false, false>(w_q, nullptr, h6, qv);
        h2 q01 = {(_Float16)(qv[0] * QS), (_Float16)(qv[1] * QS)};
        h2 q23 = {(_Float16)(qv[2] * QS), (_Float16)(qv[3] * QS)};
        uint2 qp;
        qp.x = __builtin_bit_cast(unsigned, q01);
        qp.y = __builtin_bit_cast(unsigned, q23);
        qbuf[s] = qp;
    }
    __syncthreads();                                   // barrier 5

    // ---- attention: adjacent-lane pair (2i,2i+1) owns row r=t>>1,
    //      lane parity picks the j-half; combine via DPP shuffles ----
    const int r = t >> 1;
    const int h = t & 1;
    uint2 qp = qbuf[r];
    h2 q01 = __builtin_bit_cast(h2, qp.x);
    h2 q23 = __builtin_bit_cast(h2, qp.y);

    const uint4* __restrict__ base = kvbuf + h * 64;
    float d = 0.f, a0 = 0.f, a1 = 0.f, a2 = 0.f, a3 = 0.f;
    #pragma unroll 8
    for (int j = 0; j < 64; ++j) {
        uint4 c = base[j];      // 2 addresses per wave -> free broadcast
        h2 k01 = __builtin_bit_cast(h2, c.x);
        h2 k23 = __builtin_bit_cast(h2, c.y);
        float sc = dot2acc(q01, k01, dot2acc(q23, k23, 0.f));
        float e = fexp2(sc);
        d += e;
        a0 = fma_mix_lo(c.z, e, a0);
        a1 = fma_mix_hi(c.z, e, a1);
        a2 = fma_mix_lo(c.w, e, a2);
        a3 = fma_mix_hi(c.w, e, a3);
    }
    d  += __shfl_xor(d, 1);
    a0 += __shfl_xor(a0, 1);
    a1 += __shfl_xor(a1, 1);
    a2 += __shfl_xor(a2, 1);
    a3 += __shfl_xor(a3, 1);

    float inv = fast_rcp(d);
    float z = b_fc[0];
    z = fmaf(a0 * inv, w_fc[0], z);
    z = fmaf(a1 * inv, w_fc[1], z);
    z = fmaf(a2 * inv, w_fc[2], z);
    z = fmaf(a3 * inv, w_fc[3], z);
    if (h == 0) out[(size_t)b * 128 + (size_t)r] = fast_sigmoid(z);
}

extern "C" void kernel_launch(void* const* d_in, const int* in_sizes, int n_in,
                              void* d_out, int out_size, void* d_ws, size_t ws_size,
                              hipStream_t stream) {
    const float* x    = (const float*)d_in[0];
    const float* w_fm = (const float*)d_in[1];
    const float* b_fm = (const float*)d_in[2];
    const float* w_c1 = (const float*)d_in[3];
    const float* b_c1 = (const float*)d_in[4];
    const float* w_p1 = (const float*)d_in[5];
    const float* b_p1 = (const float*)d_in[6];
    const float* w_c2 = (const float*)d_in[7];
    const float* b_c2 = (const float*)d_in[8];
    const float* w_p2 = (const float*)d_in[9];
    const float* b_p2 = (const float*)d_in[10];
    const float* w_c3 = (const float*)d_in[11];
    const float* b_c3 = (const float*)d_in[12];
    const float* w_q  = (const float*)d_in[13];
    const float* w_k  = (const float*)d_in[14];
    const float* w_v  = (const float*)d_in[15];
    const float* w_fc = (const float*)d_in[16];
    const float* b_fc = (const float*)d_in[17];
    float* out = (float*)d_out;

    dim3 grid(2048);   // one workgroup per batch
    dim3 block(256);   // 2 threads per token (halves in different waves)
    qcnn_fused_kernel<<<grid, block, 0, stream>>>(
        x, w_fm, b_fm, w_c1, b_c1, w_p1, b_p1, w_c2, b_c2,
        w_p2, b_p2, w_c3, b_c3, w_q, w_k, w_v, w_fc, b_fc, out);
}

// Round 4
// 26.003 us; speedup vs baseline: 1.0102x; 1.0102x over previous
//
#include <hip/hip_runtime.h>

#define DEV __device__ __forceinline__

typedef _Float16 h2 __attribute__((ext_vector_type(2)));
typedef float    f2 __attribute__((ext_vector_type(2)));

DEV float fast_rcp(float x) { return __builtin_amdgcn_rcpf(x); }

DEV float fexp2(float x) {
#if __has_builtin(__builtin_amdgcn_exp2f)
    return __builtin_amdgcn_exp2f(x);
#else
    float r; asm("v_exp_f32 %0, %1" : "=v"(r) : "v"(x)); return r;
#endif
}

DEV float dot2acc(h2 a, h2 b, float c) {
#if __has_builtin(__builtin_amdgcn_fdot2)
    return __builtin_amdgcn_fdot2(a, b, c, false);
#else
    return c + (float)a.x * (float)b.x + (float)a.y * (float)b.y;
#endif
}

// tanh(x) = 1 - 2/(exp2(2*log2e*x)+1); saturates correctly at +/-inf.
DEV float fast_tanh(float x) {
    float e = fexp2(x * 2.885390082f);
    return 1.0f - 2.0f * fast_rcp(e + 1.0f);
}
DEV float fast_sigmoid(float x) {
    return fast_rcp(1.0f + fexp2(x * -1.442695041f));
}

// ---- packed-weight table layout in d_ws (float2 units) ----
// entry (layer, i, p) at OFF + i*(OUT/2) + p, value = (w[2p][i], w[2p+1][i])
#define OFF_FM   0    // IN=8,  OUT=16 -> 64
#define OFF_C1   64   // IN=16, OUT=16 -> 128
#define OFF_P1   192  // IN=16, OUT=12 -> 96
#define OFF_C2   288  // IN=12, OUT=8  -> 48
#define OFF_P2   336  // IN=8,  OUT=4  -> 16
#define OFF_C3   352  // IN=4,  OUT=4  -> 8
#define OFF_Q    360  // IN=4,  OUT=4  -> 8
#define OFF_K    368  // IN=4,  OUT=4  -> 8
#define OFF_WVFC 376  // 2 entries: folded w_fc^T * W_v (4 floats)
#define N_ENTRIES 378

__global__ void qcnn_prep_kernel(const float* __restrict__ w_fm,
                                 const float* __restrict__ w_c1,
                                 const float* __restrict__ w_p1,
                                 const float* __restrict__ w_c2,
                                 const float* __restrict__ w_p2,
                                 const float* __restrict__ w_c3,
                                 const float* __restrict__ w_q,
                                 const float* __restrict__ w_k,
                                 const float* __restrict__ w_v,
                                 const float* __restrict__ w_fc,
                                 f2* __restrict__ ws) {
    int e = threadIdx.x;
    if (e >= N_ENTRIES) return;

    if (e >= OFF_WVFC) {
        int c = (e - OFF_WVFC) * 2;   // 0 or 2
        f2 r;
        r.x = w_fc[0]*w_v[0*4+c]   + w_fc[1]*w_v[1*4+c]   + w_fc[2]*w_v[2*4+c]   + w_fc[3]*w_v[3*4+c];
        r.y = w_fc[0]*w_v[0*4+c+1] + w_fc[1]*w_v[1*4+c+1] + w_fc[2]*w_v[2*4+c+1] + w_fc[3]*w_v[3*4+c+1];
        ws[e] = r;
        return;
    }

    const float* w; int IN, OH, local;
    if      (e < OFF_C1) { w = w_fm; IN = 8;  OH = 8; local = e - OFF_FM; }
    else if (e < OFF_P1) { w = w_c1; IN = 16; OH = 8; local = e - OFF_C1; }
    else if (e < OFF_C2) { w = w_p1; IN = 16; OH = 6; local = e - OFF_P1; }
    else if (e < OFF_P2) { w = w_c2; IN = 12; OH = 4; local = e - OFF_C2; }
    else if (e < OFF_C3) { w = w_p2; IN = 8;  OH = 2; local = e - OFF_P2; }
    else if (e < OFF_Q)  { w = w_c3; IN = 4;  OH = 2; local = e - OFF_C3; }
    else if (e < OFF_K)  { w = w_q;  IN = 4;  OH = 2; local = e - OFF_Q; }
    else                 { w = w_k;  IN = 4;  OH = 2; local = e - OFF_K; }
    int i = local / OH;
    int p = local % OH;
    f2 r;
    r.x = w[(2*p)   * IN + i];
    r.y = w[(2*p+1) * IN + i];
    ws[e] = r;
}

// MLP layer on packed pair weights; 1 v_pk_fma_f32 per (i, output-pair).
template <int IN, int OUT, bool HAS_BIAS, bool TANH>
DEV void layer_pk(const f2* __restrict__ wp, const float* __restrict__ bias,
                  const float (&in)[IN], float (&out)[OUT]) {
    constexpr int OH = OUT / 2;
    f2 acc[OH];
    #pragma unroll
    for (int p = 0; p < OH; ++p)
        acc[p] = HAS_BIAS ? *reinterpret_cast<const f2*>(bias + 2 * p) : f2{0.f, 0.f};
    #pragma unroll
    for (int i = 0; i < IN; ++i) {
        f2 inb = {in[i], in[i]};
        #pragma unroll
        for (int p = 0; p < OH; ++p)
            acc[p] = wp[i * OH + p] * inb + acc[p];   // v_pk_fma_f32
    }
    #pragma unroll
    for (int p = 0; p < OH; ++p) {
        out[2*p]   = TANH ? fast_tanh(acc[p].x) : acc[p].x;
        out[2*p+1] = TANH ? fast_tanh(acc[p].y) : acc[p].y;
    }
}

__global__ __launch_bounds__(128)
void qcnn_fused_kernel(const float* __restrict__ x,
                       const float* __restrict__ b_fm, const float* __restrict__ b_c1,
                       const float* __restrict__ b_p1, const float* __restrict__ b_c2,
                       const float* __restrict__ b_p2, const float* __restrict__ b_c3,
                       const float* __restrict__ b_fc,
                       const f2* __restrict__ wpk,
                       float* __restrict__ out) {
    const int b = blockIdx.x;    // batch
    const int t = threadIdx.x;   // token 0..127

    // kv entry per token: x=k01(fp16x2) y=k23(fp16x2) z=u(f32) w=unused
    __shared__ uint4 kvbuf[128];

    const float* xp = x + ((size_t)b * 128 + (size_t)t) * 8;
    float4 x0 = *reinterpret_cast<const float4*>(xp);
    float4 x1 = *reinterpret_cast<const float4*>(xp + 4);
    float xin[8] = {x0.x, x0.y, x0.z, x0.w, x1.x, x1.y, x1.z, x1.w};

    float h1[16], h2a[16], h3[12], h4[8], h5[4], h6[4];
    layer_pk<8, 16, true, true>(wpk + OFF_FM, b_fm, xin, h1);
    layer_pk<16, 16, true, true>(wpk + OFF_C1, b_c1, h1, h2a);
    layer_pk<16, 12, true, true>(wpk + OFF_P1, b_p1, h2a, h3);
    layer_pk<12, 8, true, true>(wpk + OFF_C2, b_c2, h3, h4);
    layer_pk<8, 4, true, true>(wpk + OFF_P2, b_p2, h4, h5);
    layer_pk<4, 4, true, true>(wpk + OFF_C3, b_c3, h5, h6);

    float qv[4], kk[4];
    layer_pk<4, 4, false, false>(wpk + OFF_Q, nullptr, h6, qv);
    layer_pk<4, 4, false, false>(wpk + OFF_K, nullptr, h6, kk);

    // u = (w_fc^T W_v) . h6   (fc folded into V reduction)
    f2 wv0 = wpk[OFF_WVFC], wv1 = wpk[OFF_WVFC + 1];
    float u = fmaf(wv0.x, h6[0], fmaf(wv0.y, h6[1], fmaf(wv1.x, h6[2], wv1.y * h6[3])));

    h2 pk01 = {(_Float16)kk[0], (_Float16)kk[1]};
    h2 pk23 = {(_Float16)kk[2], (_Float16)kk[3]};
    uint4 ent;
    ent.x = __builtin_bit_cast(unsigned, pk01);
    ent.y = __builtin_bit_cast(unsigned, pk23);
    ent.z = __builtin_bit_cast(unsigned, u);
    ent.w = 0;
    kvbuf[t] = ent;

    // q scaled by log2(e)/sqrt(4): folds softmax scale and exp->exp2
    const float QS = 0.7213475204f;
    h2 q01 = {(_Float16)(qv[0] * QS), (_Float16)(qv[1] * QS)};
    h2 q23 = {(_Float16)(qv[2] * QS), (_Float16)(qv[3] * QS)};

    __syncthreads();

    // lane pair (2p,2p+1) covers rows {2p,2p+1}; parity picks j-half
    unsigned q01u = __builtin_bit_cast(unsigned, q01);
    unsigned q23u = __builtin_bit_cast(unsigned, q23);
    unsigned q01o = __shfl_xor(q01u, 1);
    unsigned q23o = __shfl_xor(q23u, 1);
    const bool odd = (t & 1);
    h2 q01_r0 = __builtin_bit_cast(h2, odd ? q01o : q01u);
    h2 q23_r0 = __builtin_bit_cast(h2, odd ? q23o : q23u);
    h2 q01_r1 = __builtin_bit_cast(h2, odd ? q01u : q01o);
    h2 q23_r1 = __builtin_bit_cast(h2, odd ? q23u : q23o);

    const uint4* __restrict__ base = kvbuf + (odd ? 64 : 0);
    float d0 = 0.f, d1 = 0.f, s0acc = 0.f, s1acc = 0.f;
    #pragma unroll 8
    for (int j = 0; j < 64; ++j) {
        uint4 c = base[j];       // 2 addresses/wave -> free broadcast
        h2 k01 = __builtin_bit_cast(h2, c.x);
        h2 k23 = __builtin_bit_cast(h2, c.y);
        float uj = __builtin_bit_cast(float, c.z);
        float s0 = dot2acc(q01_r0, k01, dot2acc(q23_r0, k23, 0.f));
        float s1 = dot2acc(q01_r1, k01, dot2acc(q23_r1, k23, 0.f));
        float e0 = fexp2(s0);
        float e1 = fexp2(s1);
        d0 += e0;                 d1 += e1;
        s0acc = fmaf(e0, uj, s0acc);
        s1acc = fmaf(e1, uj, s1acc);
    }
    d0    += __shfl_xor(d0, 1);    d1    += __shfl_xor(d1, 1);
    s0acc += __shfl_xor(s0acc, 1); s1acc += __shfl_xor(s1acc, 1);

    float dd = odd ? d1 : d0;
    float uu = odd ? s1acc : s0acc;
    float z = uu * fast_rcp(dd) + b_fc[0];
    out[(size_t)b * 128 + (size_t)t] = fast_sigmoid(z);
}

extern "C" void kernel_launch(void* const* d_in, const int* in_sizes, int n_in,
                              void* d_out, int out_size, void* d_ws, size_t ws_size,
                              hipStream_t stream) {
    const float* x    = (const float*)d_in[0];
    const float* w_fm = (const float*)d_in[1];
    const float* b_fm = (const float*)d_in[2];
    const float* w_c1 = (const float*)d_in[3];
    const float* b_c1 = (const float*)d_in[4];
    const float* w_p1 = (const float*)d_in[5];
    const float* b_p1 = (const float*)d_in[6];
    const float* w_c2 = (const float*)d_in[7];
    const float* b_c2 = (const float*)d_in[8];
    const float* w_p2 = (const float*)d_in[9];
    const float* b_p2 = (const float*)d_in[10];
    const float* w_c3 = (const float*)d_in[11];
    const float* b_c3 = (const float*)d_in[12];
    const float* w_q  = (const float*)d_in[13];
    const float* w_k  = (const float*)d_in[14];
    const float* w_v  = (const float*)d_in[15];
    const float* w_fc = (const float*)d_in[16];
    const float* b_fc = (const float*)d_in[17];
    float* out = (float*)d_out;
    f2* wpk = (f2*)d_ws;

    qcnn_prep_kernel<<<1, 384, 0, stream>>>(w_fm, w_c1, w_p1, w_c2, w_p2, w_c3,
                                            w_q, w_k, w_v, w_fc, wpk);

    dim3 grid(2048);   // one workgroup per batch
    dim3 block(128);   // one thread per token
    qcnn_fused_kernel<<<grid, block, 0, stream>>>(
        x, b_fm, b_c1, b_p1, b_c2, b_p2, b_c3, b_fc, wpk, out);
}

// Round 5
// 21.361 us; speedup vs baseline: 1.2297x; 1.2173x over previous
//
#include <hip/hip_runtime.h>

#define DEV __device__ __forceinline__

typedef _Float16 h2 __attribute__((ext_vector_type(2)));

DEV float fast_rcp(float x) { return __builtin_amdgcn_rcpf(x); }

DEV float fexp2(float x) {
#if __has_builtin(__builtin_amdgcn_exp2f)
    return __builtin_amdgcn_exp2f(x);
#else
    float r; asm("v_exp_f32 %0, %1" : "=v"(r) : "v"(x)); return r;
#endif
}

DEV float dot2acc(h2 a, h2 b, float c) {
#if __has_builtin(__builtin_amdgcn_fdot2)
    return __builtin_amdgcn_fdot2(a, b, c, false);
#else
    return c + (float)a.x * (float)b.x + (float)a.y * (float)b.y;
#endif
}

// tanh(x) = 1 - 2/(exp2(2*log2e*x)+1); saturates correctly at +/-inf.
DEV float fast_tanh(float x) {
    float e = fexp2(x * 2.885390082f);
    return 1.0f - 2.0f * fast_rcp(e + 1.0f);
}
DEV float fast_sigmoid(float x) {
    return fast_rcp(1.0f + fexp2(x * -1.442695041f));
}

template <int IN, int OUT, bool HAS_BIAS, bool TANH>
DEV void layer(const float* __restrict__ w, const float* __restrict__ b,
               const float (&in)[IN], float (&out)[OUT]) {
    #pragma unroll
    for (int o = 0; o < OUT; ++o) {
        float acc = HAS_BIAS ? b[o] : 0.0f;
        #pragma unroll
        for (int i = 0; i < IN; ++i) acc = fmaf(in[i], w[o * IN + i], acc);
        out[o] = TANH ? fast_tanh(acc) : acc;
    }
}

__global__ __launch_bounds__(256)
void qcnn_fused_kernel(const float* __restrict__ x,
                       const float* __restrict__ w_fm, const float* __restrict__ b_fm,
                       const float* __restrict__ w_c1, const float* __restrict__ b_c1,
                       const float* __restrict__ w_p1, const float* __restrict__ b_p1,
                       const float* __restrict__ w_c2, const float* __restrict__ b_c2,
                       const float* __restrict__ w_p2, const float* __restrict__ b_p2,
                       const float* __restrict__ w_c3, const float* __restrict__ b_c3,
                       const float* __restrict__ w_q,  const float* __restrict__ w_k,
                       const float* __restrict__ w_v,
                       const float* __restrict__ w_fc, const float* __restrict__ b_fc,
                       float* __restrict__ out) {
    const int t     = threadIdx.x;          // 0..255
    const int bb    = t >> 7;               // sub-batch 0/1 within block
    const int tok   = t & 127;              // token 0..127
    const int batch = blockIdx.x * 2 + bb;  // 0..2047

    // per-sub-batch KV: x=k01(fp16x2) y=k23(fp16x2) z=u(f32) w=pad
    __shared__ uint4 kvbuf[2][128];

    // ---- load x[batch][tok][0:8] (coalesced, 32 B/thread) ----
    const float* xp = x + ((size_t)batch * 128 + tok) * 8;
    float4 x0 = *reinterpret_cast<const float4*>(xp);
    float4 x1 = *reinterpret_cast<const float4*>(xp + 4);
    float xin[8] = {x0.x, x0.y, x0.z, x0.w, x1.x, x1.y, x1.z, x1.w};

    // ---- MLP tower in registers; weights via uniform scalar loads ----
    float h1[16], h2a[16], h3[12], h4[8], h5[4], h6[4];
    layer<8, 16, true, true>(w_fm, b_fm, xin, h1);
    layer<16, 16, true, true>(w_c1, b_c1, h1, h2a);
    layer<16, 12, true, true>(w_p1, b_p1, h2a, h3);
    layer<12, 8, true, true>(w_c2, b_c2, h3, h4);
    layer<8, 4, true, true>(w_p2, b_p2, h4, h5);
    layer<4, 4, true, true>(w_c3, b_c3, h5, h6);

    float qv[4], kk[4];
    layer<4, 4, false, false>(w_q, nullptr, h6, qv);
    layer<4, 4, false, false>(w_k, nullptr, h6, kk);

    // ---- fc folded into V: u = (w_fc^T W_v) . h6 (uniform weights, 16+4 FMA) ----
    float wf[4];
    #pragma unroll
    for (int i = 0; i < 4; ++i)
        wf[i] = fmaf(w_fc[0], w_v[0 * 4 + i],
                fmaf(w_fc[1], w_v[1 * 4 + i],
                fmaf(w_fc[2], w_v[2 * 4 + i], w_fc[3] * w_v[3 * 4 + i])));
    float u = fmaf(wf[0], h6[0], fmaf(wf[1], h6[1], fmaf(wf[2], h6[2], wf[3] * h6[3])));

    h2 pk01 = {(_Float16)kk[0], (_Float16)kk[1]};
    h2 pk23 = {(_Float16)kk[2], (_Float16)kk[3]};
    uint4 ent;
    ent.x = __builtin_bit_cast(unsigned, pk01);
    ent.y = __builtin_bit_cast(unsigned, pk23);
    ent.z = __builtin_bit_cast(unsigned, u);
    ent.w = 0;
    kvbuf[bb][tok] = ent;

    // q scaled by log2(e)/sqrt(4): folds softmax scale and exp->exp2
    const float QS = 0.7213475204f;
    h2 q01 = {(_Float16)(qv[0] * QS), (_Float16)(qv[1] * QS)};
    h2 q23 = {(_Float16)(qv[2] * QS), (_Float16)(qv[3] * QS)};

    __syncthreads();

    // ---- attention: adjacent-lane pair covers rows {tok&~1, tok|1};
    //      parity picks the j-half; combine via shfl_xor(1) ----
    unsigned q01u = __builtin_bit_cast(unsigned, q01);
    unsigned q23u = __builtin_bit_cast(unsigned, q23);
    unsigned q01o = __shfl_xor(q01u, 1);
    unsigned q23o = __shfl_xor(q23u, 1);
    const bool odd = (t & 1);
    h2 q01_r0 = __builtin_bit_cast(h2, odd ? q01o : q01u);
    h2 q23_r0 = __builtin_bit_cast(h2, odd ? q23o : q23u);
    h2 q01_r1 = __builtin_bit_cast(h2, odd ? q01u : q01o);
    h2 q23_r1 = __builtin_bit_cast(h2, odd ? q23u : q23o);

    const uint4* __restrict__ base = kvbuf[bb] + (odd ? 64 : 0);
    float d0 = 0.f, d1 = 0.f, s0acc = 0.f, s1acc = 0.f;
    #pragma unroll 8
    for (int j = 0; j < 64; ++j) {
        uint4 c = base[j];       // 2 addresses/wave -> free broadcast
        h2 k01 = __builtin_bit_cast(h2, c.x);
        h2 k23 = __builtin_bit_cast(h2, c.y);
        float uj = __builtin_bit_cast(float, c.z);
        float s0 = dot2acc(q01_r0, k01, dot2acc(q23_r0, k23, 0.f));
        float s1 = dot2acc(q01_r1, k01, dot2acc(q23_r1, k23, 0.f));
        float e0 = fexp2(s0);
        float e1 = fexp2(s1);
        d0 += e0;                 d1 += e1;
        s0acc = fmaf(e0, uj, s0acc);
        s1acc = fmaf(e1, uj, s1acc);
    }
    d0    += __shfl_xor(d0, 1);    d1    += __shfl_xor(d1, 1);
    s0acc += __shfl_xor(s0acc, 1); s1acc += __shfl_xor(s1acc, 1);

    float dd = odd ? d1 : d0;
    float uu = odd ? s1acc : s0acc;
    float z = uu * fast_rcp(dd) + b_fc[0];
    out[(size_t)batch * 128 + tok] = fast_sigmoid(z);
}

extern "C" void kernel_launch(void* const* d_in, const int* in_sizes, int n_in,
                              void* d_out, int out_size, void* d_ws, size_t ws_size,
                              hipStream_t stream) {
    const float* x    = (const float*)d_in[0];
    const float* w_fm = (const float*)d_in[1];
    const float* b_fm = (const float*)d_in[2];
    const float* w_c1 = (const float*)d_in[3];
    const float* b_c1 = (const float*)d_in[4];
    const float* w_p1 = (const float*)d_in[5];
    const float* b_p1 = (const float*)d_in[6];
    const float* w_c2 = (const float*)d_in[7];
    const float* b_c2 = (const float*)d_in[8];
    const float* w_p2 = (const float*)d_in[9];
    const float* b_p2 = (const float*)d_in[10];
    const float* w_c3 = (const float*)d_in[11];
    const float* b_c3 = (const float*)d_in[12];
    const float* w_q  = (const float*)d_in[13];
    const float* w_k  = (const float*)d_in[14];
    const float* w_v  = (const float*)d_in[15];
    const float* w_fc = (const float*)d_in[16];
    const float* b_fc = (const float*)d_in[17];
    float* out = (float*)d_out;

    dim3 grid(1024);   // 2 batches per workgroup
    dim3 block(256);
    qcnn_fused_kernel<<<grid, block, 0, stream>>>(
        x, w_fm, b_fm, w_c1, b_c1, w_p1, b_p1, w_c2, b_c2,
        w_p2, b_p2, w_c3, b_c3, w_q, w_k, w_v, w_fc, b_fc, out);
}